// Round 11
// baseline (753.926 us; speedup 1.0000x reference)
//
#include <hip/hip_runtime.h>
#include <math.h>

#define GRID_SZ 128
#define NC 196
#define NC4 49                // NC/4 float4 per row
#define G2 (GRID_SZ*GRID_SZ)  // 16384
#define UPTS 128              // sorted points per wave in gather (divides N)
#define KB 21                 // spatial key bits: gx<<14 | gy<<7 | gz

// ---------------- wave-aggregated atomic helpers ----------------

__device__ __forceinline__ void agg_hist(int bin, bool valid, int lane,
                                         unsigned int* __restrict__ hist) {
    unsigned long long todo = __ballot(valid);
    while (todo) {
        const int leader = __ffsll((long long)todo) - 1;
        const int lb = __shfl(bin, leader);
        const unsigned long long match = __ballot(valid && bin == lb);
        if (lane == leader) atomicAdd(&hist[lb], (unsigned)__popcll(match));
        todo &= ~match;
    }
}

// ---------------- K1: per-point triple key + histograms ----------------

__global__ __launch_bounds__(256) void key_hist_kernel(
    const float* __restrict__ gs, const float* __restrict__ sb,
    unsigned int* __restrict__ keys, unsigned int* __restrict__ hist21,
    unsigned int* __restrict__ hist, int B, int N) {
    const long long P = (long long)B * N;
    const long long p = (long long)blockIdx.x * blockDim.x + threadIdx.x;
    const bool valid = (p < P);
    const int lane = threadIdx.x & 63;

    int key = -1, bin0 = -1, bin1 = -1, bin2 = -1;
    if (valid) {
        const int b = (int)(p / N);
        const float4 head = *(const float4*)(gs + (size_t)p * NC);

        const float i0 = 1.0f / (sb[1] - sb[0]);
        const float i1 = 1.0f / (sb[3] - sb[2]);
        const float i2 = 1.0f / (sb[5] - sb[4]);
        int gx = (int)((head.x - sb[0]) * i0 * 127.0f);
        int gy = (int)((head.y - sb[2]) * i1 * 127.0f);
        int gz = (int)((head.z - sb[4]) * i2 * 127.0f);
        gx = min(127, max(0, gx));
        gy = min(127, max(0, gy));
        gz = min(127, max(0, gz));

        key = (b << KB) | (gx << 14) | (gy << 7) | gz;
        keys[p] = (unsigned)key;
        bin0 = (b * 3 + 0) * G2 + (gx * GRID_SZ + gy);
        bin1 = (b * 3 + 1) * G2 + (gx * GRID_SZ + gz);
        bin2 = (b * 3 + 2) * G2 + (gy * GRID_SZ + gz);
    }
    agg_hist(key, valid, lane, hist21);
    agg_hist(bin0, valid, lane, hist);
    agg_hist(bin1, valid, lane, hist);
    agg_hist(bin2, valid, lane, hist);
}

// ---------------- K2: fused scans ----------------

// blocks [0, blocks21): scan hist21 chunk -> cur21 (excl) + part1[blk]
// blocks [blocks21, ...): occupancy scan of hist -> cid (excl) + partO[blk']
__global__ __launch_bounds__(256) void scanAf_kernel(
    const unsigned int* __restrict__ hist21, unsigned int* __restrict__ cur21,
    unsigned int* __restrict__ part1, int n21, int blocks21,
    const unsigned int* __restrict__ hist, int* __restrict__ cid,
    unsigned int* __restrict__ partO, int nO) {
    __shared__ unsigned int s[256];
    const int t = threadIdx.x;
    if ((int)blockIdx.x < blocks21) {
        const int g = blockIdx.x * 256 + t;
        const unsigned v = (g < n21) ? hist21[g] : 0u;
        s[t] = v;
        __syncthreads();
        for (int off = 1; off < 256; off <<= 1) {
            const unsigned u = (t >= off) ? s[t - off] : 0u;
            __syncthreads();
            s[t] += u;
            __syncthreads();
        }
        if (g < n21) cur21[g] = s[t] - v;
        if (t == 255) part1[blockIdx.x] = s[255];
    } else {
        const int blk = (int)blockIdx.x - blocks21;
        const int g = blk * 256 + t;
        const unsigned v = (g < nO && hist[g] > 0u) ? 1u : 0u;
        s[t] = v;
        __syncthreads();
        for (int off = 1; off < 256; off <<= 1) {
            const unsigned u = (t >= off) ? s[t - off] : 0u;
            __syncthreads();
            s[t] += u;
            __syncthreads();
        }
        if (g < nO) cid[g] = (int)(s[t] - v);
        if (t == 255) partO[blk] = s[255];
    }
}

// block 0: sequential carry-scan over part1[n1] (in place, exclusive)
// block 1: exclusive scan of partO[nO] + write total
__global__ __launch_bounds__(1024) void scanBf_kernel(
    unsigned int* __restrict__ part1, int n1,
    unsigned int* __restrict__ partO, int nO,
    unsigned int* __restrict__ total) {
    __shared__ unsigned int s[1024];
    const int t = threadIdx.x;
    if (blockIdx.x == 0) {
        unsigned carry = 0;
        for (int base = 0; base < n1; base += 1024) {
            const int g = base + t;
            const unsigned v = (g < n1) ? part1[g] : 0u;
            s[t] = v;
            __syncthreads();
            for (int off = 1; off < 1024; off <<= 1) {
                const unsigned u = (t >= off) ? s[t - off] : 0u;
                __syncthreads();
                s[t] += u;
                __syncthreads();
            }
            if (g < n1) part1[g] = s[t] - v + carry;
            carry += s[1023];
            __syncthreads();
        }
    } else {
        const unsigned v = (t < nO) ? partO[t] : 0u;
        s[t] = v;
        __syncthreads();
        for (int off = 1; off < 1024; off <<= 1) {
            const unsigned u = (t >= off) ? s[t - off] : 0u;
            __syncthreads();
            s[t] += u;
            __syncthreads();
        }
        if (t < nO) partO[t] = s[t] - v;
        if (t == nO - 1 && total != nullptr) *total = s[t];
    }
}

__global__ __launch_bounds__(256) void scanCf_kernel(
    unsigned int* __restrict__ cur21, const unsigned int* __restrict__ part1,
    int n21, int blocks21,
    int* __restrict__ cid, const unsigned int* __restrict__ partO, int nO) {
    const int t = threadIdx.x;
    if ((int)blockIdx.x < blocks21) {
        const int g = blockIdx.x * 256 + t;
        if (g < n21) cur21[g] += part1[blockIdx.x];
    } else {
        const int blk = (int)blockIdx.x - blocks21;
        const int g = blk * 256 + t;
        if (g < nO) cid[g] += (int)partO[blk];
    }
}

// ---------------- zero kernels ----------------

__global__ void zero_kernel(float4* __restrict__ p, long long n4) {
    long long i = (long long)blockIdx.x * blockDim.x + threadIdx.x;
    long long stride = (long long)gridDim.x * blockDim.x;
    const float4 z = make_float4(0.f, 0.f, 0.f, 0.f);
    for (; i < n4; i += stride) p[i] = z;
}

__global__ void zero_dyn_kernel(float4* __restrict__ nwc4, float* __restrict__ dnc,
                                const unsigned int* __restrict__ total) {
    const unsigned T = *total;
    const long long n4 = (long long)T * NC4;
    long long i = (long long)blockIdx.x * blockDim.x + threadIdx.x;
    const long long stride = (long long)gridDim.x * blockDim.x;
    const float4 z = make_float4(0.f, 0.f, 0.f, 0.f);
    for (long long k = i; k < n4; k += stride) nwc4[k] = z;
    for (long long k = i; k < (long long)T; k += stride) dnc[k] = 0.f;
}

// ---------------- K3: scatter into triple-sorted order (packed meta) --------

__global__ __launch_bounds__(256) void scatter3_kernel(
    const unsigned int* __restrict__ keys, unsigned int* __restrict__ cur21,
    uint2* __restrict__ meta2, int B, int N) {
    const long long P = (long long)B * N;
    const long long p = (long long)blockIdx.x * blockDim.x + threadIdx.x;
    const bool valid = (p < P);
    const int lane = threadIdx.x & 63;

    int key = -1, n = 0;
    if (valid) {
        const int b = (int)(p / N);
        n = (int)(p - (long long)b * N);
        key = (int)keys[p];
    }

    unsigned long long todo = __ballot(valid);
    while (todo) {
        const int leader = __ffsll((long long)todo) - 1;
        const int lk = __shfl(key, leader);
        const unsigned long long match = __ballot(valid && key == lk);
        unsigned base = 0;
        if (lane == leader) base = atomicAdd(&cur21[lk], (unsigned)__popcll(match));
        base = __shfl((int)base, leader);
        if (valid && key == lk) {
            const unsigned rank = (unsigned)__popcll(match & ((1ull << lane) - 1ull));
            meta2[base + rank] = make_uint2((unsigned)n, (unsigned)key);
        }
        todo &= ~match;
    }
}

// ---------------- K4: depth-4 batched triple-sorted gather-reduce --------

__device__ __forceinline__ void flush3(int key, const int* __restrict__ cid,
                                       const float4& acc, float accD,
                                       float* __restrict__ nwc, float* __restrict__ dnc,
                                       int lane) {
    if (key < 0) return;
    const int b = key >> KB;
    const int gx = (key >> 14) & 127;
    const int gy = (key >> 7) & 127;
    const int gz = key & 127;
    const int cc0 = cid[(b * 3 + 0) * G2 + gx * GRID_SZ + gy];
    const int cc1 = cid[(b * 3 + 1) * G2 + gx * GRID_SZ + gz];
    const int cc2 = cid[(b * 3 + 2) * G2 + gy * GRID_SZ + gz];
    if (lane < NC4) {
        float* b0 = nwc + (size_t)cc0 * NC + 4 * lane;
        float* b1 = nwc + (size_t)cc1 * NC + 4 * lane;
        float* b2 = nwc + (size_t)cc2 * NC + 4 * lane;
        unsafeAtomicAdd(b0 + 0, acc.x); unsafeAtomicAdd(b0 + 1, acc.y);
        unsafeAtomicAdd(b0 + 2, acc.z); unsafeAtomicAdd(b0 + 3, acc.w);
        unsafeAtomicAdd(b1 + 0, acc.x); unsafeAtomicAdd(b1 + 1, acc.y);
        unsafeAtomicAdd(b1 + 2, acc.z); unsafeAtomicAdd(b1 + 3, acc.w);
        unsafeAtomicAdd(b2 + 0, acc.x); unsafeAtomicAdd(b2 + 1, acc.y);
        unsafeAtomicAdd(b2 + 2, acc.z); unsafeAtomicAdd(b2 + 3, acc.w);
    } else if (lane == NC4) {
        unsafeAtomicAdd(dnc + cc0, accD);
        unsafeAtomicAdd(dnc + cc1, accD);
        unsafeAtomicAdd(dnc + cc2, accD);
    }
}

__global__ __launch_bounds__(256) void gather3_kernel(
    const float* __restrict__ gs, const float* __restrict__ sb,
    const uint2* __restrict__ meta2, const int* __restrict__ cid,
    float* __restrict__ nwc, float* __restrict__ dnc,
    int N, long long P) {
    const int lane = threadIdx.x & 63;
    const long long wave = (long long)blockIdx.x * 4 + (threadIdx.x >> 6);
    const long long i0 = wave * (long long)UPTS;
    if (i0 >= P) return;
    // N % UPTS == 0 -> chunk stays within one batch

    const uint2* mt = meta2 + i0;
    const bool ld = (lane < NC4);
    const float4 f40 = make_float4(0.f, 0.f, 0.f, 0.f);

    // meta pipeline: A = current group, B = next group
    uint2 mA0 = mt[0], mA1 = mt[1], mA2 = mt[2], mA3 = mt[3];
    uint2 mB0 = mt[4], mB1 = mt[5], mB2 = mt[6], mB3 = mt[7];

    const int b = (int)(mA0.y >> KB);                  // wave-constant
    const float4* brows = (const float4*)gs + (size_t)b * N * NC4;

    const float lo0 = sb[0], hi0 = sb[1];
    const float lo1 = sb[2], hi1 = sb[3];
    const float lo2 = sb[4], hi2 = sb[5];
    const float s0 = 2.0f / (hi0 - lo0);
    const float s1 = 2.0f / (hi1 - lo1);
    const float s2 = 2.0f / (hi2 - lo2);

    // rows + heads for group 0
    const float4* p0 = brows + (size_t)mA0.x * NC4;
    const float4* p1 = brows + (size_t)mA1.x * NC4;
    const float4* p2 = brows + (size_t)mA2.x * NC4;
    const float4* p3 = brows + (size_t)mA3.x * NC4;
    float4 v0 = ld ? p0[lane] : f40; float4 h0 = p0[0];
    float4 v1 = ld ? p1[lane] : f40; float4 h1 = p1[0];
    float4 v2 = ld ? p2[lane] : f40; float4 h2 = p2[0];
    float4 v3 = ld ? p3[lane] : f40; float4 h3 = p3[0];

    int curKey = -1;
    float4 acc = f40;
    float accD = 0.f;

#define CONSUME(V, H, KEY)                                                  \
    {                                                                       \
        const float cnx = (H.x - lo0) * s0 - 1.0f;                          \
        const float cny = (H.y - lo1) * s1 - 1.0f;                          \
        const float cnz = (H.z - lo2) * s2 - 1.0f;                          \
        const float alpha = 1.0f / (1.0f + __expf(-H.w));                   \
        float4 vv = V;                                                      \
        if (lane == 0) { vv.x = cnx; vv.y = cny; vv.z = cnz; }              \
        const float4 av = make_float4(vv.x * alpha, vv.y * alpha,           \
                                      vv.z * alpha, vv.w * alpha);          \
        if ((int)(KEY) != curKey) {                                         \
            flush3(curKey, cid, acc, accD, nwc, dnc, lane);                 \
            curKey = (int)(KEY); acc = av; accD = alpha;                    \
        } else {                                                            \
            acc.x += av.x; acc.y += av.y; acc.z += av.z; acc.w += av.w;     \
            accD += alpha;                                                  \
        }                                                                   \
    }

    for (int j = 0; j < UPTS; j += 4) {
        // 1) batch-issue row+head loads for group j+4 (unconditional)
        const float4* q0 = brows + (size_t)mB0.x * NC4;
        const float4* q1 = brows + (size_t)mB1.x * NC4;
        const float4* q2 = brows + (size_t)mB2.x * NC4;
        const float4* q3 = brows + (size_t)mB3.x * NC4;
        float4 t0 = ld ? q0[lane] : f40; float4 g0 = q0[0];
        float4 t1 = ld ? q1[lane] : f40; float4 g1 = q1[0];
        float4 t2 = ld ? q2[lane] : f40; float4 g2 = q2[0];
        float4 t3 = ld ? q3[lane] : f40; float4 g3 = q3[0];

        // 2) prefetch meta for group j+8 (clamped -> no conditionals)
        const int m0 = (j + 8  < UPTS) ? j + 8  : UPTS - 1;
        const int m1 = (j + 9  < UPTS) ? j + 9  : UPTS - 1;
        const int m2 = (j + 10 < UPTS) ? j + 10 : UPTS - 1;
        const int m3 = (j + 11 < UPTS) ? j + 11 : UPTS - 1;
        const uint2 mT0 = mt[m0], mT1 = mt[m1], mT2 = mt[m2], mT3 = mt[m3];

        // 3) consume current group (registers loaded last iteration)
        CONSUME(v0, h0, mA0.y);
        CONSUME(v1, h1, mA1.y);
        CONSUME(v2, h2, mA2.y);
        CONSUME(v3, h3, mA3.y);

        // 4) rotate pipeline
        v0 = t0; v1 = t1; v2 = t2; v3 = t3;
        h0 = g0; h1 = g1; h2 = g2; h3 = g3;
        mA0 = mB0; mA1 = mB1; mA2 = mB2; mA3 = mB3;
        mB0 = mT0; mB1 = mT1; mB2 = mT2; mB3 = mT3;
    }
    flush3(curKey, cid, acc, accD, nwc, dnc, lane);
#undef CONSUME
}

// ---------------- K5: transpose + normalize from compact ----------------

#define TCELLS 64
__global__ __launch_bounds__(256) void xpose_c_kernel(
    const float* __restrict__ nwc, const float* __restrict__ dnc,
    const int* __restrict__ cid, const unsigned int* __restrict__ hist,
    float* __restrict__ out) {
    __shared__ float tile[TCELLS][197];   // pad: conflict-free column reads
    __shared__ float dinv[TCELLS];
    __shared__ int scid[TCELLS];
    const int t = threadIdx.x;
    const int pg = blockIdx.x >> 8;              // plane index (256 tiles/plane)
    const int c0 = (blockIdx.x & 255) * TCELLS;

    if (t < TCELLS) {
        const int bin = pg * G2 + c0 + t;
        const int cc = (hist[bin] > 0u) ? cid[bin] : -1;
        scid[t] = cc;
        dinv[t] = (cc >= 0) ? 1.0f / fmaxf(dnc[cc], 1e-6f) : 0.0f;
    }
    __syncthreads();

    const float4 f40 = make_float4(0.f, 0.f, 0.f, 0.f);
    for (int i = t; i < TCELLS * NC4; i += 256) {
        const int cell = i / NC4;
        const int cp = i - cell * NC4;
        const int cc = scid[cell];
        float4 v = (cc >= 0) ? ((const float4*)(nwc + (size_t)cc * NC))[cp] : f40;
        float* dst = &tile[cell][cp * 4];
        dst[0] = v.x; dst[1] = v.y; dst[2] = v.z; dst[3] = v.w;
    }
    __syncthreads();

    float* obase = out + (size_t)pg * NC * G2 + c0;
    for (int i = t; i < TCELLS * NC; i += 256) {
        const int c = i >> 6;
        const int cell = i & 63;
        obase[(size_t)c * G2 + cell] = tile[cell][c] * dinv[cell];
    }
}

// ---------------- fallback (direct channel-major, R1-style) ----------------

struct Slot { int tag; float den; float4 acc; };

__device__ __forceinline__ void slot_flush(const Slot& s, float* __restrict__ out,
                                           float* __restrict__ den,
                                           size_t outPlaneBase, int denPlaneBase, int lane) {
    if (s.tag < 0) return;
    if (lane < NC4) {
        size_t base = outPlaneBase + (size_t)(4 * lane) * G2 + (size_t)s.tag;
        unsafeAtomicAdd(out + base,                s.acc.x);
        unsafeAtomicAdd(out + base + (size_t)G2,   s.acc.y);
        unsafeAtomicAdd(out + base + (size_t)2*G2, s.acc.z);
        unsafeAtomicAdd(out + base + (size_t)3*G2, s.acc.w);
    }
    if (lane == 0) unsafeAtomicAdd(den + denPlaneBase + s.tag, s.den);
}

__device__ __forceinline__ void plane_acc(Slot& a, Slot& b, int cell, float alpha,
                                          const float4& av,
                                          float* __restrict__ out, float* __restrict__ den,
                                          size_t outPlaneBase, int denPlaneBase, int lane) {
    if (cell == a.tag) {
        a.acc.x += av.x; a.acc.y += av.y; a.acc.z += av.z; a.acc.w += av.w; a.den += alpha;
    } else if (cell == b.tag) {
        b.acc.x += av.x; b.acc.y += av.y; b.acc.z += av.z; b.acc.w += av.w; b.den += alpha;
    } else {
        if (b.den > a.den) { Slot t = a; a = b; b = t; }
        slot_flush(b, out, den, outPlaneBase, denPlaneBase, lane);
        b.tag = cell; b.den = alpha; b.acc = av;
    }
}

__global__ __launch_bounds__(256) void splat_kernel(
    const float* __restrict__ gs, const float* __restrict__ sb,
    float* __restrict__ out, float* __restrict__ den, int B, int N, int ppw) {
    const int lane = threadIdx.x & 63;
    const long long wave = (long long)blockIdx.x * (blockDim.x >> 6) + (threadIdx.x >> 6);
    const long long totalPts = (long long)B * N;
    long long start = wave * ppw;
    if (start >= totalPts) return;
    long long end = start + ppw;
    if (end > totalPts) end = totalPts;
    const int bb = (int)(start / N);

    const float lo0 = sb[0], hi0 = sb[1];
    const float lo1 = sb[2], hi1 = sb[3];
    const float lo2 = sb[4], hi2 = sb[5];
    const float s0 = 2.0f / (hi0 - lo0);
    const float s1 = 2.0f / (hi1 - lo1);
    const float s2 = 2.0f / (hi2 - lo2);

    const size_t ob0 = ((size_t)(bb * 3 + 0) * NC) * G2;
    const size_t ob1 = ((size_t)(bb * 3 + 1) * NC) * G2;
    const size_t ob2 = ((size_t)(bb * 3 + 2) * NC) * G2;
    const int db0 = (bb * 3 + 0) * G2;
    const int db1 = (bb * 3 + 1) * G2;
    const int db2 = (bb * 3 + 2) * G2;

    const float4 f40 = make_float4(0.f, 0.f, 0.f, 0.f);
    Slot a0{-1,0.f,f40}, t0{-1,0.f,f40}, a1{-1,0.f,f40}, t1{-1,0.f,f40},
         a2{-1,0.f,f40}, t2{-1,0.f,f40};

    const float4* rows = (const float4*)gs;
    const float4* r0 = rows + (size_t)start * NC4;
    float4 v = (lane < NC4) ? r0[lane] : f40;
    float4 h = r0[0];

    for (long long i = start; i < end; ++i) {
        float4 vn = f40, hn = f40;
        if (i + 1 < end) {
            const float4* rn = rows + (size_t)(i + 1) * NC4;
            vn = (lane < NC4) ? rn[lane] : f40;
            hn = rn[0];
        }
        const float cnx = (h.x - lo0) * s0 - 1.0f;
        const float cny = (h.y - lo1) * s1 - 1.0f;
        const float cnz = (h.z - lo2) * s2 - 1.0f;
        int gx = (int)((cnx * 0.5f + 0.5f) * 127.0f);
        int gy = (int)((cny * 0.5f + 0.5f) * 127.0f);
        int gz = (int)((cnz * 0.5f + 0.5f) * 127.0f);
        gx = min(127, max(0, gx)); gy = min(127, max(0, gy)); gz = min(127, max(0, gz));
        const int cxy = __builtin_amdgcn_readfirstlane(gx * GRID_SZ + gy);
        const int cxz = __builtin_amdgcn_readfirstlane(gx * GRID_SZ + gz);
        const int cyz = __builtin_amdgcn_readfirstlane(gy * GRID_SZ + gz);
        const float alpha = 1.0f / (1.0f + __expf(-h.w));
        float4 vv = v;
        if (lane == 0) { vv.x = cnx; vv.y = cny; vv.z = cnz; }
        const float4 av = make_float4(vv.x*alpha, vv.y*alpha, vv.z*alpha, vv.w*alpha);
        plane_acc(a0, t0, cxy, alpha, av, out, den, ob0, db0, lane);
        plane_acc(a1, t1, cxz, alpha, av, out, den, ob1, db1, lane);
        plane_acc(a2, t2, cyz, alpha, av, out, den, ob2, db2, lane);
        v = vn; h = hn;
    }
    slot_flush(a0, out, den, ob0, db0, lane);
    slot_flush(t0, out, den, ob0, db0, lane);
    slot_flush(a1, out, den, ob1, db1, lane);
    slot_flush(t1, out, den, ob1, db1, lane);
    slot_flush(a2, out, den, ob2, db2, lane);
    slot_flush(t2, out, den, ob2, db2, lane);
}

__global__ void normalize_kernel(float* __restrict__ out, const float* __restrict__ den,
                                 int total4) {
    int idx = blockIdx.x * blockDim.x + threadIdx.x;
    const int stride = gridDim.x * blockDim.x;
    for (; idx < total4; idx += stride) {
        float4 v = ((float4*)out)[idx];
        const int e = idx * 4;
        const int cell = e & (G2 - 1);
        const int bp = e / (NC * G2);
        const float4 d = *(const float4*)(den + bp * G2 + cell);
        v.x /= fmaxf(d.x, 1e-6f);
        v.y /= fmaxf(d.y, 1e-6f);
        v.z /= fmaxf(d.z, 1e-6f);
        v.w /= fmaxf(d.w, 1e-6f);
        ((float4*)out)[idx] = v;
    }
}

// ---------------- launch ----------------

extern "C" void kernel_launch(void* const* d_in, const int* in_sizes, int n_in,
                              void* d_out, int out_size, void* d_ws, size_t ws_size,
                              hipStream_t stream) {
    const float* gs = (const float*)d_in[0];
    const float* sb = (const float*)d_in[1];
    float* out = (float*)d_out;

    const int B = out_size / (3 * NC * G2);                            // 4
    const int N = (int)((long long)in_sizes[0] / ((long long)B * NC)); // 131072
    const long long P = (long long)B * N;                              // 524288
    const int NB = B * 3 * G2;                                         // 196608
    const long long NB21 = (long long)B << KB;                         // 8.4M

    const size_t nwF = (size_t)NB * NC;
    const size_t dnF = (size_t)NB;
    size_t off = 0;
    const size_t o_nw = off;      off += nwF * 4;
    const size_t o_dn = off;      off += dnF * 4;
    const size_t o_hist21 = off;  off += (size_t)NB21 * 4;   // contiguous with hist
    const size_t o_hist = off;    off += (size_t)NB * 4;
    const size_t o_cur21 = off;   off += (size_t)NB21 * 4;
    const size_t o_cid = off;     off += (size_t)NB * 4;
    const size_t o_part1 = off;   off += ((size_t)NB21 / 256 + 256) * 4;
    const size_t o_partO = off;   off += 1024 * 4;
    const size_t o_total = off;   off += 256;
    const size_t o_keys = off;    off += (size_t)P * 4;
    const size_t o_meta2 = off;   off += (size_t)P * 8;
    const size_t need = off;

    const int blocks21 = (int)(NB21 / 256);      // 32768 (NB21 multiple of 256)
    const int nPartO = (NB + 255) / 256;         // 768

    if (ws_size >= need && B <= 64 && nPartO <= 1024 &&
        (N % UPTS) == 0 && (NB21 % 256) == 0) {
        char* ws = (char*)d_ws;
        float* nwc = (float*)(ws + o_nw);
        float* dnc = (float*)(ws + o_dn);
        unsigned int* hist21 = (unsigned int*)(ws + o_hist21);
        unsigned int* hist = (unsigned int*)(ws + o_hist);
        unsigned int* cur21 = (unsigned int*)(ws + o_cur21);
        int* cid = (int*)(ws + o_cid);
        unsigned int* part1 = (unsigned int*)(ws + o_part1);
        unsigned int* partO = (unsigned int*)(ws + o_partO);
        unsigned int* total = (unsigned int*)(ws + o_total);
        unsigned int* keys = (unsigned int*)(ws + o_keys);
        uint2* meta2 = (uint2*)(ws + o_meta2);

        // zero hist21 + hist (contiguous)
        zero_kernel<<<2048, 256, 0, stream>>>((float4*)hist21,
                                              (NB21 + (long long)NB) / 4);

        const int pBlocks = (int)((P + 255) / 256);                    // 2048
        key_hist_kernel<<<pBlocks, 256, 0, stream>>>(gs, sb, keys, hist21, hist, B, N);

        // fused scans: level-1 (hist21 + occ), level-2 (part1 carry + partO/total),
        // then add-back
        scanAf_kernel<<<blocks21 + nPartO, 256, 0, stream>>>(
            hist21, cur21, part1, (int)NB21, blocks21, hist, cid, partO, NB);
        scanBf_kernel<<<2, 1024, 0, stream>>>(part1, blocks21, partO, nPartO, total);
        scanCf_kernel<<<blocks21 + nPartO, 256, 0, stream>>>(
            cur21, part1, (int)NB21, blocks21, cid, partO, NB);

        zero_dyn_kernel<<<2048, 256, 0, stream>>>((float4*)nwc, dnc, total);

        scatter3_kernel<<<pBlocks, 256, 0, stream>>>(keys, cur21, meta2, B, N);

        const long long gWaves = P / UPTS;                             // 4096
        const int gBlocks = (int)((gWaves + 3) / 4);                   // 1024
        gather3_kernel<<<gBlocks, 256, 0, stream>>>(gs, sb, meta2, cid,
                                                    nwc, dnc, N, P);

        const int xblocks = B * 3 * (G2 / TCELLS);                     // 3072
        xpose_c_kernel<<<xblocks, 256, 0, stream>>>(nwc, dnc, cid, hist, out);
    } else {
        float* den = (float*)d_ws;
        const long long out4 = (long long)out_size / 4;
        const long long den4 = (long long)dnF / 4;
        const int ppw = 64;
        const long long waves = ((long long)B * N) / ppw;
        const int blocks = (int)((waves + 3) / 4);
        zero_kernel<<<2048, 256, 0, stream>>>((float4*)out, out4);
        zero_kernel<<<256, 256, 0, stream>>>((float4*)den, den4);
        splat_kernel<<<blocks, 256, 0, stream>>>(gs, sb, out, den, B, N, ppw);
        normalize_kernel<<<4096, 256, 0, stream>>>(out, den, (int)out4);
    }
}

// Round 12
// 583.509 us; speedup vs baseline: 1.2921x; 1.2921x over previous
//
#include <hip/hip_runtime.h>
#include <math.h>

#define GRID_SZ 128
#define NC 196
#define NC4 49                // NC/4 float4 per row
#define G2 (GRID_SZ*GRID_SZ)  // 16384
#define UPTS 64               // sorted points per wave in gather (divides N)
#define KB 21                 // spatial key bits: gx<<14 | gy<<7 | gz
#define RPW 128               // partial records per wave in reduce pass
#define EMPTYK 0xFFFFFFFFu

// ---------------- wave-aggregated atomic helpers ----------------

__device__ __forceinline__ void agg_hist(int bin, bool valid, int lane,
                                         unsigned int* __restrict__ hist) {
    unsigned long long todo = __ballot(valid);
    while (todo) {
        const int leader = __ffsll((long long)todo) - 1;
        const int lb = __shfl(bin, leader);
        const unsigned long long match = __ballot(valid && bin == lb);
        if (lane == leader) atomicAdd(&hist[lb], (unsigned)__popcll(match));
        todo &= ~match;
    }
}

// ---------------- K1: per-point triple key + histograms ----------------

__global__ __launch_bounds__(256) void key_hist_kernel(
    const float* __restrict__ gs, const float* __restrict__ sb,
    unsigned int* __restrict__ keys, unsigned int* __restrict__ hist21,
    unsigned int* __restrict__ hist, int B, int N) {
    const long long P = (long long)B * N;
    const long long p = (long long)blockIdx.x * blockDim.x + threadIdx.x;
    const bool valid = (p < P);
    const int lane = threadIdx.x & 63;

    int key = -1, bin0 = -1, bin1 = -1, bin2 = -1;
    if (valid) {
        const int b = (int)(p / N);
        const float4 head = *(const float4*)(gs + (size_t)p * NC);

        const float i0 = 1.0f / (sb[1] - sb[0]);
        const float i1 = 1.0f / (sb[3] - sb[2]);
        const float i2 = 1.0f / (sb[5] - sb[4]);
        int gx = (int)((head.x - sb[0]) * i0 * 127.0f);
        int gy = (int)((head.y - sb[2]) * i1 * 127.0f);
        int gz = (int)((head.z - sb[4]) * i2 * 127.0f);
        gx = min(127, max(0, gx));
        gy = min(127, max(0, gy));
        gz = min(127, max(0, gz));

        key = (b << KB) | (gx << 14) | (gy << 7) | gz;
        keys[p] = (unsigned)key;
        bin0 = (b * 3 + 0) * G2 + (gx * GRID_SZ + gy);
        bin1 = (b * 3 + 1) * G2 + (gx * GRID_SZ + gz);
        bin2 = (b * 3 + 2) * G2 + (gy * GRID_SZ + gz);
    }
    agg_hist(key, valid, lane, hist21);
    agg_hist(bin0, valid, lane, hist);
    agg_hist(bin1, valid, lane, hist);
    agg_hist(bin2, valid, lane, hist);
}

// ---------------- K2: fused scans ----------------

__global__ __launch_bounds__(256) void scanAf_kernel(
    const unsigned int* __restrict__ hist21, unsigned int* __restrict__ cur21,
    unsigned int* __restrict__ part1, int n21, int blocks21,
    const unsigned int* __restrict__ hist, int* __restrict__ cid,
    unsigned int* __restrict__ partO, int nO) {
    __shared__ unsigned int s[256];
    const int t = threadIdx.x;
    if ((int)blockIdx.x < blocks21) {
        const int g = blockIdx.x * 256 + t;
        const unsigned v = (g < n21) ? hist21[g] : 0u;
        s[t] = v;
        __syncthreads();
        for (int off = 1; off < 256; off <<= 1) {
            const unsigned u = (t >= off) ? s[t - off] : 0u;
            __syncthreads();
            s[t] += u;
            __syncthreads();
        }
        if (g < n21) cur21[g] = s[t] - v;
        if (t == 255) part1[blockIdx.x] = s[255];
    } else {
        const int blk = (int)blockIdx.x - blocks21;
        const int g = blk * 256 + t;
        const unsigned v = (g < nO && hist[g] > 0u) ? 1u : 0u;
        s[t] = v;
        __syncthreads();
        for (int off = 1; off < 256; off <<= 1) {
            const unsigned u = (t >= off) ? s[t - off] : 0u;
            __syncthreads();
            s[t] += u;
            __syncthreads();
        }
        if (g < nO) cid[g] = (int)(s[t] - v);
        if (t == 255) partO[blk] = s[255];
    }
}

__global__ __launch_bounds__(1024) void scanBf_kernel(
    unsigned int* __restrict__ part1, int n1,
    unsigned int* __restrict__ partO, int nO,
    unsigned int* __restrict__ total) {
    __shared__ unsigned int s[1024];
    const int t = threadIdx.x;
    if (blockIdx.x == 0) {
        unsigned carry = 0;
        for (int base = 0; base < n1; base += 1024) {
            const int g = base + t;
            const unsigned v = (g < n1) ? part1[g] : 0u;
            s[t] = v;
            __syncthreads();
            for (int off = 1; off < 1024; off <<= 1) {
                const unsigned u = (t >= off) ? s[t - off] : 0u;
                __syncthreads();
                s[t] += u;
                __syncthreads();
            }
            if (g < n1) part1[g] = s[t] - v + carry;
            carry += s[1023];
            __syncthreads();
        }
    } else {
        const unsigned v = (t < nO) ? partO[t] : 0u;
        s[t] = v;
        __syncthreads();
        for (int off = 1; off < 1024; off <<= 1) {
            const unsigned u = (t >= off) ? s[t - off] : 0u;
            __syncthreads();
            s[t] += u;
            __syncthreads();
        }
        if (t < nO) partO[t] = s[t] - v;
        if (t == nO - 1 && total != nullptr) *total = s[t];
    }
}

__global__ __launch_bounds__(256) void scanCf_kernel(
    unsigned int* __restrict__ cur21, const unsigned int* __restrict__ part1,
    int n21, int blocks21,
    int* __restrict__ cid, const unsigned int* __restrict__ partO, int nO) {
    const int t = threadIdx.x;
    if ((int)blockIdx.x < blocks21) {
        const int g = blockIdx.x * 256 + t;
        if (g < n21) cur21[g] += part1[blockIdx.x];
    } else {
        const int blk = (int)blockIdx.x - blocks21;
        const int g = blk * 256 + t;
        if (g < nO) cid[g] += (int)partO[blk];
    }
}

// ---------------- zero kernels ----------------

__global__ void zero_kernel(float4* __restrict__ p, long long n4) {
    long long i = (long long)blockIdx.x * blockDim.x + threadIdx.x;
    long long stride = (long long)gridDim.x * blockDim.x;
    const float4 z = make_float4(0.f, 0.f, 0.f, 0.f);
    for (; i < n4; i += stride) p[i] = z;
}

__global__ void zero_dyn_kernel(float4* __restrict__ nwc4, float* __restrict__ dnc,
                                const unsigned int* __restrict__ total) {
    const unsigned T = *total;
    const long long n4 = (long long)T * NC4;
    long long i = (long long)blockIdx.x * blockDim.x + threadIdx.x;
    const long long stride = (long long)gridDim.x * blockDim.x;
    const float4 z = make_float4(0.f, 0.f, 0.f, 0.f);
    for (long long k = i; k < n4; k += stride) nwc4[k] = z;
    for (long long k = i; k < (long long)T; k += stride) dnc[k] = 0.f;
}

// ---------------- K3: scatter into triple-sorted order (packed meta) --------

__global__ __launch_bounds__(256) void scatter3_kernel(
    const unsigned int* __restrict__ keys, unsigned int* __restrict__ cur21,
    uint2* __restrict__ meta2, int B, int N) {
    const long long P = (long long)B * N;
    const long long p = (long long)blockIdx.x * blockDim.x + threadIdx.x;
    const bool valid = (p < P);
    const int lane = threadIdx.x & 63;

    int key = -1, n = 0;
    if (valid) {
        const int b = (int)(p / N);
        n = (int)(p - (long long)b * N);
        key = (int)keys[p];
    }

    unsigned long long todo = __ballot(valid);
    while (todo) {
        const int leader = __ffsll((long long)todo) - 1;
        const int lk = __shfl(key, leader);
        const unsigned long long match = __ballot(valid && key == lk);
        unsigned base = 0;
        if (lane == leader) base = atomicAdd(&cur21[lk], (unsigned)__popcll(match));
        base = __shfl((int)base, leader);
        if (valid && key == lk) {
            const unsigned rank = (unsigned)__popcll(match & ((1ull << lane) - 1ull));
            meta2[base + rank] = make_uint2((unsigned)n, (unsigned)key);
        }
        todo &= ~match;
    }
}

// ---------------- shared flush helpers ----------------

__device__ __forceinline__ void flush3(int key, const int* __restrict__ cid,
                                       const float4& acc, float accD,
                                       float* __restrict__ nwc, float* __restrict__ dnc,
                                       int lane) {
    if (key < 0) return;
    const int b = key >> KB;
    const int gx = (key >> 14) & 127;
    const int gy = (key >> 7) & 127;
    const int gz = key & 127;
    const int cc0 = cid[(b * 3 + 0) * G2 + gx * GRID_SZ + gy];
    const int cc1 = cid[(b * 3 + 1) * G2 + gx * GRID_SZ + gz];
    const int cc2 = cid[(b * 3 + 2) * G2 + gy * GRID_SZ + gz];
    if (lane < NC4) {
        float* b0 = nwc + (size_t)cc0 * NC + 4 * lane;
        float* b1 = nwc + (size_t)cc1 * NC + 4 * lane;
        float* b2 = nwc + (size_t)cc2 * NC + 4 * lane;
        unsafeAtomicAdd(b0 + 0, acc.x); unsafeAtomicAdd(b0 + 1, acc.y);
        unsafeAtomicAdd(b0 + 2, acc.z); unsafeAtomicAdd(b0 + 3, acc.w);
        unsafeAtomicAdd(b1 + 0, acc.x); unsafeAtomicAdd(b1 + 1, acc.y);
        unsafeAtomicAdd(b1 + 2, acc.z); unsafeAtomicAdd(b1 + 3, acc.w);
        unsafeAtomicAdd(b2 + 0, acc.x); unsafeAtomicAdd(b2 + 1, acc.y);
        unsafeAtomicAdd(b2 + 2, acc.z); unsafeAtomicAdd(b2 + 3, acc.w);
    } else if (lane == NC4) {
        unsafeAtomicAdd(dnc + cc0, accD);
        unsafeAtomicAdd(dnc + cc1, accD);
        unsafeAtomicAdd(dnc + cc2, accD);
    }
}

__device__ __forceinline__ void store_partial(long long slot, int key,
                                              const float4& acc, float accD,
                                              unsigned* __restrict__ kpart,
                                              float* __restrict__ apart, int lane) {
    float* base = apart + slot * 200;
    if (lane < NC4) *(float4*)(base + 4 * lane) = acc;
    else if (lane == NC4) base[NC] = accD;
    if (lane == 0) kpart[slot] = (unsigned)key;
}

// ---------------- K4: depth-1 gather-reduce, contention-free flushes --------

__global__ __launch_bounds__(256) void gather3_kernel(
    const float* __restrict__ gs, const float* __restrict__ sb,
    const uint2* __restrict__ meta2, const int* __restrict__ cid,
    float* __restrict__ nwc, float* __restrict__ dnc,
    unsigned* __restrict__ kpart, float* __restrict__ apart,
    int N, long long P) {
    const int lane = threadIdx.x & 63;
    const long long wave = (long long)blockIdx.x * 4 + (threadIdx.x >> 6);
    const long long i0 = wave * (long long)UPTS;
    if (i0 >= P) return;
    // N % UPTS == 0 -> chunk stays within one batch (P multiple of UPTS)

    const uint2* mt = meta2 + i0;
    const bool ld = (lane < NC4);
    const float4 f40 = make_float4(0.f, 0.f, 0.f, 0.f);

    uint2 mA = mt[0];
    uint2 mB = mt[1];

    const int b = (int)(mA.y >> KB);                  // wave-constant
    const float4* brows = (const float4*)gs + (size_t)b * N * NC4;

    const float lo0 = sb[0], hi0 = sb[1];
    const float lo1 = sb[2], hi1 = sb[3];
    const float lo2 = sb[4], hi2 = sb[5];
    const float s0 = 2.0f / (hi0 - lo0);
    const float s1 = 2.0f / (hi1 - lo1);
    const float s2 = 2.0f / (hi2 - lo2);

    const float4* pA = brows + (size_t)mA.x * NC4;
    float4 v = ld ? pA[lane] : f40;
    float4 h = pA[0];

    int curKey = -1;
    float4 acc = f40;
    float accD = 0.f;
    bool first = true;   // current run is the first run of this chunk

    for (int j = 0; j < UPTS; ++j) {
        // issue next row (clamped tail -> redundant reload, harmless)
        const float4* pN = brows + (size_t)mB.x * NC4;
        float4 vn = ld ? pN[lane] : f40;
        float4 hn = pN[0];

        // prefetch meta j+2
        const int m = (j + 2 < UPTS) ? j + 2 : UPTS - 1;
        const uint2 mT = mt[m];

        // consume point j
        const float cnx = (h.x - lo0) * s0 - 1.0f;
        const float cny = (h.y - lo1) * s1 - 1.0f;
        const float cnz = (h.z - lo2) * s2 - 1.0f;
        const float alpha = 1.0f / (1.0f + __expf(-h.w));
        float4 vv = v;
        if (lane == 0) { vv.x = cnx; vv.y = cny; vv.z = cnz; }
        const float4 av = make_float4(vv.x * alpha, vv.y * alpha,
                                      vv.z * alpha, vv.w * alpha);
        const int kA = (int)mA.y;
        if (kA != curKey) {
            if (curKey >= 0) {
                if (first) {
                    // first run of chunk -> partial record (no atomics)
                    store_partial(2 * wave, curKey, acc, accD, kpart, apart, lane);
                    first = false;
                } else {
                    // interior run: key owned by exactly this wave -> uncontended
                    flush3(curKey, cid, acc, accD, nwc, dnc, lane);
                }
            }
            curKey = kA; acc = av; accD = alpha;
        } else {
            acc.x += av.x; acc.y += av.y; acc.z += av.z; acc.w += av.w;
            accD += alpha;
        }

        v = vn; h = hn;
        mA = mB; mB = mT;
    }
    // final run
    if (first) {
        store_partial(2 * wave, curKey, acc, accD, kpart, apart, lane);
        if (lane == 0) kpart[2 * wave + 1] = EMPTYK;
    } else {
        store_partial(2 * wave + 1, curKey, acc, accD, kpart, apart, lane);
    }
}

// ---------------- K4b: reduce boundary partials (key-sorted stream) --------

__global__ __launch_bounds__(256) void reduce_part_kernel(
    const unsigned* __restrict__ kpart, const float* __restrict__ apart,
    const int* __restrict__ cid,
    float* __restrict__ nwc, float* __restrict__ dnc, long long S) {
    const int lane = threadIdx.x & 63;
    const long long wave = (long long)blockIdx.x * 4 + (threadIdx.x >> 6);
    const long long r0 = wave * (long long)RPW;
    if (r0 >= S) return;
    long long r1 = r0 + RPW;
    if (r1 > S) r1 = S;

    const float4 f40 = make_float4(0.f, 0.f, 0.f, 0.f);
    int curKey = -1;
    float4 acc = f40;
    float accD = 0.f;

    for (long long r = r0; r < r1; ++r) {
        const unsigned k = kpart[r];
        if (k == EMPTYK) continue;
        const float* base = apart + r * 200;
        float4 rv = (lane < NC4) ? ((const float4*)base)[lane] : f40;
        const float rd = base[NC];
        if ((int)k != curKey) {
            flush3(curKey, cid, acc, accD, nwc, dnc, lane);
            curKey = (int)k; acc = rv; accD = rd;
        } else {
            acc.x += rv.x; acc.y += rv.y; acc.z += rv.z; acc.w += rv.w;
            accD += rd;
        }
    }
    flush3(curKey, cid, acc, accD, nwc, dnc, lane);
}

// ---------------- K5: transpose + normalize from compact ----------------

#define TCELLS 64
__global__ __launch_bounds__(256) void xpose_c_kernel(
    const float* __restrict__ nwc, const float* __restrict__ dnc,
    const int* __restrict__ cid, const unsigned int* __restrict__ hist,
    float* __restrict__ out) {
    __shared__ float tile[TCELLS][197];   // pad: conflict-free column reads
    __shared__ float dinv[TCELLS];
    __shared__ int scid[TCELLS];
    const int t = threadIdx.x;
    const int pg = blockIdx.x >> 8;              // plane index (256 tiles/plane)
    const int c0 = (blockIdx.x & 255) * TCELLS;

    if (t < TCELLS) {
        const int bin = pg * G2 + c0 + t;
        const int cc = (hist[bin] > 0u) ? cid[bin] : -1;
        scid[t] = cc;
        dinv[t] = (cc >= 0) ? 1.0f / fmaxf(dnc[cc], 1e-6f) : 0.0f;
    }
    __syncthreads();

    const float4 f40 = make_float4(0.f, 0.f, 0.f, 0.f);
    for (int i = t; i < TCELLS * NC4; i += 256) {
        const int cell = i / NC4;
        const int cp = i - cell * NC4;
        const int cc = scid[cell];
        float4 v = (cc >= 0) ? ((const float4*)(nwc + (size_t)cc * NC))[cp] : f40;
        float* dst = &tile[cell][cp * 4];
        dst[0] = v.x; dst[1] = v.y; dst[2] = v.z; dst[3] = v.w;
    }
    __syncthreads();

    float* obase = out + (size_t)pg * NC * G2 + c0;
    for (int i = t; i < TCELLS * NC; i += 256) {
        const int c = i >> 6;
        const int cell = i & 63;
        obase[(size_t)c * G2 + cell] = tile[cell][c] * dinv[cell];
    }
}

// ---------------- fallback (direct channel-major, R1-style) ----------------

struct Slot { int tag; float den; float4 acc; };

__device__ __forceinline__ void slot_flush(const Slot& s, float* __restrict__ out,
                                           float* __restrict__ den,
                                           size_t outPlaneBase, int denPlaneBase, int lane) {
    if (s.tag < 0) return;
    if (lane < NC4) {
        size_t base = outPlaneBase + (size_t)(4 * lane) * G2 + (size_t)s.tag;
        unsafeAtomicAdd(out + base,                s.acc.x);
        unsafeAtomicAdd(out + base + (size_t)G2,   s.acc.y);
        unsafeAtomicAdd(out + base + (size_t)2*G2, s.acc.z);
        unsafeAtomicAdd(out + base + (size_t)3*G2, s.acc.w);
    }
    if (lane == 0) unsafeAtomicAdd(den + denPlaneBase + s.tag, s.den);
}

__device__ __forceinline__ void plane_acc(Slot& a, Slot& b, int cell, float alpha,
                                          const float4& av,
                                          float* __restrict__ out, float* __restrict__ den,
                                          size_t outPlaneBase, int denPlaneBase, int lane) {
    if (cell == a.tag) {
        a.acc.x += av.x; a.acc.y += av.y; a.acc.z += av.z; a.acc.w += av.w; a.den += alpha;
    } else if (cell == b.tag) {
        b.acc.x += av.x; b.acc.y += av.y; b.acc.z += av.z; b.acc.w += av.w; b.den += alpha;
    } else {
        if (b.den > a.den) { Slot t = a; a = b; b = t; }
        slot_flush(b, out, den, outPlaneBase, denPlaneBase, lane);
        b.tag = cell; b.den = alpha; b.acc = av;
    }
}

__global__ __launch_bounds__(256) void splat_kernel(
    const float* __restrict__ gs, const float* __restrict__ sb,
    float* __restrict__ out, float* __restrict__ den, int B, int N, int ppw) {
    const int lane = threadIdx.x & 63;
    const long long wave = (long long)blockIdx.x * (blockDim.x >> 6) + (threadIdx.x >> 6);
    const long long totalPts = (long long)B * N;
    long long start = wave * ppw;
    if (start >= totalPts) return;
    long long end = start + ppw;
    if (end > totalPts) end = totalPts;
    const int bb = (int)(start / N);

    const float lo0 = sb[0], hi0 = sb[1];
    const float lo1 = sb[2], hi1 = sb[3];
    const float lo2 = sb[4], hi2 = sb[5];
    const float s0 = 2.0f / (hi0 - lo0);
    const float s1 = 2.0f / (hi1 - lo1);
    const float s2 = 2.0f / (hi2 - lo2);

    const size_t ob0 = ((size_t)(bb * 3 + 0) * NC) * G2;
    const size_t ob1 = ((size_t)(bb * 3 + 1) * NC) * G2;
    const size_t ob2 = ((size_t)(bb * 3 + 2) * NC) * G2;
    const int db0 = (bb * 3 + 0) * G2;
    const int db1 = (bb * 3 + 1) * G2;
    const int db2 = (bb * 3 + 2) * G2;

    const float4 f40 = make_float4(0.f, 0.f, 0.f, 0.f);
    Slot a0{-1,0.f,f40}, t0{-1,0.f,f40}, a1{-1,0.f,f40}, t1{-1,0.f,f40},
         a2{-1,0.f,f40}, t2{-1,0.f,f40};

    const float4* rows = (const float4*)gs;
    const float4* r0 = rows + (size_t)start * NC4;
    float4 v = (lane < NC4) ? r0[lane] : f40;
    float4 h = r0[0];

    for (long long i = start; i < end; ++i) {
        float4 vn = f40, hn = f40;
        if (i + 1 < end) {
            const float4* rn = rows + (size_t)(i + 1) * NC4;
            vn = (lane < NC4) ? rn[lane] : f40;
            hn = rn[0];
        }
        const float cnx = (h.x - lo0) * s0 - 1.0f;
        const float cny = (h.y - lo1) * s1 - 1.0f;
        const float cnz = (h.z - lo2) * s2 - 1.0f;
        int gx = (int)((cnx * 0.5f + 0.5f) * 127.0f);
        int gy = (int)((cny * 0.5f + 0.5f) * 127.0f);
        int gz = (int)((cnz * 0.5f + 0.5f) * 127.0f);
        gx = min(127, max(0, gx)); gy = min(127, max(0, gy)); gz = min(127, max(0, gz));
        const int cxy = __builtin_amdgcn_readfirstlane(gx * GRID_SZ + gy);
        const int cxz = __builtin_amdgcn_readfirstlane(gx * GRID_SZ + gz);
        const int cyz = __builtin_amdgcn_readfirstlane(gy * GRID_SZ + gz);
        const float alpha = 1.0f / (1.0f + __expf(-h.w));
        float4 vv = v;
        if (lane == 0) { vv.x = cnx; vv.y = cny; vv.z = cnz; }
        const float4 av = make_float4(vv.x*alpha, vv.y*alpha, vv.z*alpha, vv.w*alpha);
        plane_acc(a0, t0, cxy, alpha, av, out, den, ob0, db0, lane);
        plane_acc(a1, t1, cxz, alpha, av, out, den, ob1, db1, lane);
        plane_acc(a2, t2, cyz, alpha, av, out, den, ob2, db2, lane);
        v = vn; h = hn;
    }
    slot_flush(a0, out, den, ob0, db0, lane);
    slot_flush(t0, out, den, ob0, db0, lane);
    slot_flush(a1, out, den, ob1, db1, lane);
    slot_flush(t1, out, den, ob1, db1, lane);
    slot_flush(a2, out, den, ob2, db2, lane);
    slot_flush(t2, out, den, ob2, db2, lane);
}

__global__ void normalize_kernel(float* __restrict__ out, const float* __restrict__ den,
                                 int total4) {
    int idx = blockIdx.x * blockDim.x + threadIdx.x;
    const int stride = gridDim.x * blockDim.x;
    for (; idx < total4; idx += stride) {
        float4 v = ((float4*)out)[idx];
        const int e = idx * 4;
        const int cell = e & (G2 - 1);
        const int bp = e / (NC * G2);
        const float4 d = *(const float4*)(den + bp * G2 + cell);
        v.x /= fmaxf(d.x, 1e-6f);
        v.y /= fmaxf(d.y, 1e-6f);
        v.z /= fmaxf(d.z, 1e-6f);
        v.w /= fmaxf(d.w, 1e-6f);
        ((float4*)out)[idx] = v;
    }
}

// ---------------- launch ----------------

extern "C" void kernel_launch(void* const* d_in, const int* in_sizes, int n_in,
                              void* d_out, int out_size, void* d_ws, size_t ws_size,
                              hipStream_t stream) {
    const float* gs = (const float*)d_in[0];
    const float* sb = (const float*)d_in[1];
    float* out = (float*)d_out;

    const int B = out_size / (3 * NC * G2);                            // 4
    const int N = (int)((long long)in_sizes[0] / ((long long)B * NC)); // 131072
    const long long P = (long long)B * N;                              // 524288
    const int NB = B * 3 * G2;                                         // 196608
    const long long NB21 = (long long)B << KB;                         // 8.4M
    const long long gWaves = P / UPTS;                                 // 8192
    const long long S = 2 * gWaves;                                    // 16384 partials

    const size_t nwF = (size_t)NB * NC;
    const size_t dnF = (size_t)NB;
    size_t off = 0;
    const size_t o_nw = off;      off += nwF * 4;
    const size_t o_dn = off;      off += dnF * 4;
    const size_t o_hist21 = off;  off += (size_t)NB21 * 4;   // contiguous with hist
    const size_t o_hist = off;    off += (size_t)NB * 4;
    const size_t o_cur21 = off;   off += (size_t)NB21 * 4;
    const size_t o_cid = off;     off += (size_t)NB * 4;
    const size_t o_part1 = off;   off += ((size_t)NB21 / 256 + 256) * 4;
    const size_t o_partO = off;   off += 1024 * 4;
    const size_t o_total = off;   off += 256;
    const size_t o_keys = off;    off += (size_t)P * 4;
    const size_t o_meta2 = off;   off += (size_t)P * 8;
    const size_t o_kpart = off;   off += (size_t)S * 4;
    const size_t o_apart = off;   off += (size_t)S * 200 * 4;
    const size_t need = off;

    const int blocks21 = (int)(NB21 / 256);      // 32768 (NB21 multiple of 256)
    const int nPartO = (NB + 255) / 256;         // 768

    if (ws_size >= need && B <= 64 && nPartO <= 1024 &&
        (N % UPTS) == 0 && (NB21 % 256) == 0) {
        char* ws = (char*)d_ws;
        float* nwc = (float*)(ws + o_nw);
        float* dnc = (float*)(ws + o_dn);
        unsigned int* hist21 = (unsigned int*)(ws + o_hist21);
        unsigned int* hist = (unsigned int*)(ws + o_hist);
        unsigned int* cur21 = (unsigned int*)(ws + o_cur21);
        int* cid = (int*)(ws + o_cid);
        unsigned int* part1 = (unsigned int*)(ws + o_part1);
        unsigned int* partO = (unsigned int*)(ws + o_partO);
        unsigned int* total = (unsigned int*)(ws + o_total);
        unsigned int* keys = (unsigned int*)(ws + o_keys);
        uint2* meta2 = (uint2*)(ws + o_meta2);
        unsigned int* kpart = (unsigned int*)(ws + o_kpart);
        float* apart = (float*)(ws + o_apart);

        // zero hist21 + hist (contiguous)
        zero_kernel<<<2048, 256, 0, stream>>>((float4*)hist21,
                                              (NB21 + (long long)NB) / 4);

        const int pBlocks = (int)((P + 255) / 256);                    // 2048
        key_hist_kernel<<<pBlocks, 256, 0, stream>>>(gs, sb, keys, hist21, hist, B, N);

        scanAf_kernel<<<blocks21 + nPartO, 256, 0, stream>>>(
            hist21, cur21, part1, (int)NB21, blocks21, hist, cid, partO, NB);
        scanBf_kernel<<<2, 1024, 0, stream>>>(part1, blocks21, partO, nPartO, total);
        scanCf_kernel<<<blocks21 + nPartO, 256, 0, stream>>>(
            cur21, part1, (int)NB21, blocks21, cid, partO, NB);

        zero_dyn_kernel<<<2048, 256, 0, stream>>>((float4*)nwc, dnc, total);

        scatter3_kernel<<<pBlocks, 256, 0, stream>>>(keys, cur21, meta2, B, N);

        const int gBlocks = (int)((gWaves + 3) / 4);                   // 2048
        gather3_kernel<<<gBlocks, 256, 0, stream>>>(gs, sb, meta2, cid,
                                                    nwc, dnc, kpart, apart, N, P);

        const long long rWaves = (S + RPW - 1) / RPW;                  // 128
        const int rBlocks = (int)((rWaves + 3) / 4);                   // 32
        reduce_part_kernel<<<rBlocks, 256, 0, stream>>>(kpart, apart, cid,
                                                        nwc, dnc, S);

        const int xblocks = B * 3 * (G2 / TCELLS);                     // 3072
        xpose_c_kernel<<<xblocks, 256, 0, stream>>>(nwc, dnc, cid, hist, out);
    } else {
        float* den = (float*)d_ws;
        const long long out4 = (long long)out_size / 4;
        const long long den4 = (long long)dnF / 4;
        const int ppw = 64;
        const long long waves = ((long long)B * N) / ppw;
        const int blocks = (int)((waves + 3) / 4);
        zero_kernel<<<2048, 256, 0, stream>>>((float4*)out, out4);
        zero_kernel<<<256, 256, 0, stream>>>((float4*)den, den4);
        splat_kernel<<<blocks, 256, 0, stream>>>(gs, sb, out, den, B, N, ppw);
        normalize_kernel<<<4096, 256, 0, stream>>>(out, den, (int)out4);
    }
}